// Round 8
// baseline (2869.069 us; speedup 1.0000x reference)
//
#include <hip/hip_runtime.h>
#include <hip/hip_cooperative_groups.h>
namespace cg = cooperative_groups;

typedef unsigned int u32;

static __device__ __forceinline__ float sigf (float x){ return 1.0f/(1.0f+__expf(-x)); }
static __device__ __forceinline__ float tanh_(float x){ return 2.0f/(1.0f+__expf(-2.0f*x)) - 1.0f; }

#define NM 2730            // 273*10 distinct (t, j=b%10) rows
#define N_O0 878080        // 245*128*28

static __device__ __forceinline__ int dot4(u32 a, u32 b, int acc){
#if __has_builtin(__builtin_amdgcn_sdot4)
  return __builtin_amdgcn_sdot4((int)a, (int)b, acc, false);
#else
  int s = acc;
  #pragma unroll
  for(int i=0;i<4;i++){
    int av = (int)((signed char)((a >> (8*i)) & 0xffu));
    int bv = (int)((signed char)((b >> (8*i)) & 0xffu));
    s += av*bv;
  }
  return s;
#endif
}

struct MegaArgs {
  const float *x, *val, *alpha, *gamma, *iseas, *cats, *mp;
  const float *wi0, *wi1, *wi2, *wi3;
  const float *hh0, *hh1, *hh2, *hh3;
  const float *bs0, *bs1, *bs2, *bs3;
  const float *linW, *linb, *scW, *scb;
  float *out;
  float *ST, *lvlT, *xT, *xz, *yA, *yB;
  float *wT0, *wT1, *wT2, *wT3, *linWT, *scT, *zsc;
  u32   *W8;
};

// ---- gemm phase body: Z[m][1024] = X[m][K] @ WT[K][1024] + bias ----
// 512 threads: cols (tid, tid+512); virtual blocks of 8 rows, vb += 256.
template<bool FIRST>
__device__ __forceinline__ void gemm_body(const MegaArgs& A, char* smem,
    const float* X, const float* WT, const float* bias, float* Z){
  const int tid = threadIdx.x;
  const int bid = blockIdx.x;
  constexpr int K    = FIRST ? 49 : 256;
  constexpr int XSTR = FIRST ? 52 : 256;
  float* Xs = (float*)smem;                     // [8][XSTR]
  for(int vb = bid; vb < 342; vb += 256){
    const int m0 = vb*8;
    if(FIRST){
      for(int idx=tid; idx<8*49; idx+=512){
        int p = idx/49, f = idx - p*49;
        int m = m0 + p;
        float v = 0.f;
        if(m < NM){
          int tt = m/10, jj = m - (m/10)*10;
          if(f < 28){
            int c = tt + f;
            v = A.xT[c*128+jj] / A.ST[c*128+jj] / A.lvlT[(tt+27)*128+jj];
          } else if(f < 48){
            v = A.cats[jj*20 + (f-28)];
          } else {
            v = A.mp[0];
          }
        }
        Xs[p*XSTR + f] = v;
      }
    } else {
      for(int idx=tid; idx<2048; idx+=512){
        int p = idx >> 8, c = idx & 255;
        int m = m0 + p;
        Xs[p*XSTR + c] = (m < NM) ? X[(size_t)m*256 + c] : 0.f;
      }
    }
    __syncthreads();
    float a0[8], a1[8];
    {
      float b0 = bias[tid], b1 = bias[tid+512];
      #pragma unroll
      for(int p=0;p<8;p++){ a0[p]=b0; a1[p]=b1; }
    }
    #pragma unroll 7
    for(int f=0; f<K; f++){
      float w0 = WT[f*1024 + tid];
      float w1 = WT[f*1024 + tid + 512];
      #pragma unroll
      for(int p=0;p<8;p++){
        float xv = Xs[p*XSTR + f];
        a0[p] += w0*xv; a1[p] += w1*xv;
      }
    }
    for(int p=0;p<8;p++){
      int m = m0 + p;
      if(m < NM){
        float* zb = Z + (size_t)m*1024;
        zb[tid] = a0[p]; zb[tid+512] = a1[p];
      }
    }
    __syncthreads();
  }
}

// ---- scan phase body: champion v9 structure (pure L2 weight stream,
// 512 threads, 0.98us/step measured). bid>=chains returns to the sync. ----
__device__ __forceinline__ void scan_body(const MegaArgs& A, char* smem,
    int layer, int chains, int d, const float* Z, float* Y, const float* RES){
  const int tid = threadIdx.x;
  const int bid = blockIdx.x;
  if(bid >= chains) return;
  u32*   h8 = (u32*)smem;                       // 256 B
  int*   zp = (int*)(smem + 256);               // 16 KB [4][1024]
  float* sc = (float*)(smem + 256 + 16384);     // 4 KB
  const u32* W8 = A.W8 + (size_t)layer*65536;
  const float* zsc = A.zsc + layer*1024;
  const int j = bid % 10;
  const int r = bid / 10;
  const int ns = (273 - r + d - 1)/d;
  const int kg = tid & 127;
  const int js = tid >> 7;
  const uint4* Wb = (const uint4*)W8 + (size_t)js*4096 + kg;
  const uint4* hq = (const uint4*)h8 + js*4;

  for(int i=tid;i<1024;i+=512) sc[i] = zsc[i];
  if(tid < 64) h8[tid] = 0u;
  float cst = 0.0f;
  __syncthreads();

  int t = r;
  for(int s=0; s<ns; s++, t+=d){
    const size_t row = (size_t)(t*10 + j);
    float zv0=0.f, zv1=0.f, zv2=0.f, zv3=0.f, rv=0.f;
    if(tid < 256){                       // prefetch (consumed after barrier)
      const float* zb = Z + row*1024;
      zv0 = zb[tid]; zv1 = zb[tid+256]; zv2 = zb[tid+512]; zv3 = zb[tid+768];
      if(RES) rv = RES[row*256 + tid];
    }
    int a0=0,a1=0,a2=0,a3=0,a4=0,a5=0,a6=0,a7=0;
    #pragma unroll
    for(int q=0;q<4;q++){
      uint4 h4 = hq[q];                  // broadcast: 16 h int8
      #pragma unroll
      for(int rr=0;rr<8;rr++){
        uint4 w = Wb[rr*512 + q*128];
        int* ap = (rr==0)?&a0:(rr==1)?&a1:(rr==2)?&a2:(rr==3)?&a3:
                  (rr==4)?&a4:(rr==5)?&a5:(rr==6)?&a6:&a7;
        int acc = *ap;
        acc = dot4(w.x, h4.x, acc);
        acc = dot4(w.y, h4.y, acc);
        acc = dot4(w.z, h4.z, acc);
        acc = dot4(w.w, h4.w, acc);
        *ap = acc;
      }
    }
    zp[js*1024 +       kg] = a0;
    zp[js*1024 + 128 + kg] = a1;
    zp[js*1024 + 256 + kg] = a2;
    zp[js*1024 + 384 + kg] = a3;
    zp[js*1024 + 512 + kg] = a4;
    zp[js*1024 + 640 + kg] = a5;
    zp[js*1024 + 768 + kg] = a6;
    zp[js*1024 + 896 + kg] = a7;
    __syncthreads();
    if(tid < 256){
      const int u = tid;
      int si = zp[u]        + zp[1024+u]     + zp[2048+u]     + zp[3072+u];
      int sf = zp[u+256]    + zp[1024+u+256] + zp[2048+u+256] + zp[3072+u+256];
      int sg = zp[u+512]    + zp[1024+u+512] + zp[2048+u+512] + zp[3072+u+512];
      int so = zp[u+768]    + zp[1024+u+768] + zp[2048+u+768] + zp[3072+u+768];
      float zi = zv0 + sc[u]     * (float)si;
      float zf = zv1 + sc[u+256] * (float)sf;
      float zg = zv2 + sc[u+512] * (float)sg;
      float zo = zv3 + sc[u+768] * (float)so;
      float c  = sigf(zf)*cst + sigf(zi)*tanh_(zg);
      float h  = sigf(zo)*tanh_(c);
      cst = c;
      int hqi = __float2int_rn(h * 127.0f);
      hqi = max(-127, min(127, hqi));
      ((signed char*)h8)[u] = (signed char)hqi;
      Y[row*256 + u] = h + rv;
    }
    // LDS-only fence (champion): don't drain vmcnt; Y store drains later
    asm volatile("s_waitcnt lgkmcnt(0)\n\ts_barrier" ::: "memory");
  }
}

// ---- the mega kernel: 11 former launches as phases with grid syncs ----
__global__ __launch_bounds__(512) void k_mega(MegaArgs A){
  __shared__ __align__(16) char smem[153600];   // 150 KB arena -> 1 WG/CU
  const int tid = threadIdx.x;
  const int bid = blockIdx.x;
  cg::grid_group gg = cg::this_grid();
  #define GSYNC() do{ __threadfence(); gg.sync(); __threadfence(); }while(0)

  // ---- P0: prep (xT + 6 transposes + zsc), grid-stride 951808 items ----
  for(int i0 = bid*512 + tid; i0 < 951808; i0 += 131072){
    int i = i0;
    if(i < 38400){ int t=i>>7, b=i&127; A.xT[i] = A.x[b*300+t]; }
    else { i -= 38400;
    if(i < 50176){ int c=i/1024, r=i-c*1024; A.wT0[i] = A.wi0[r*49+c]; }
    else { i -= 50176;
    if(i < 262144){ int c=i>>10, r=i&1023; A.wT1[i] = A.wi1[r*256+c]; }
    else { i -= 262144;
    if(i < 262144){ int c=i>>10, r=i&1023; A.wT2[i] = A.wi2[r*256+c]; }
    else { i -= 262144;
    if(i < 262144){ int c=i>>10, r=i&1023; A.wT3[i] = A.wi3[r*256+c]; }
    else { i -= 262144;
    if(i < 65536){ int c=i>>8, r=i&255; A.linWT[i] = A.linW[r*256+c]; }
    else { i -= 65536;
    if(i < 7168){ int c=i/28, r=i-c*28; A.scT[i] = A.scW[r*256+c]; }
    else { i -= 7168;
    if(i < 4096){
      int l = i >> 10, r = i & 1023;
      const float* W = (l==0)?A.hh0:(l==1)?A.hh1:(l==2)?A.hh2:A.hh3;
      const float4* p4 = (const float4*)(W + (size_t)r*256);
      float m = 0.f;
      #pragma unroll 8
      for(int q=0;q<64;q++){
        float4 v = p4[q];
        m = fmaxf(m, fmaxf(fmaxf(fabsf(v.x),fabsf(v.y)), fmaxf(fabsf(v.z),fabsf(v.w))));
      }
      A.zsc[i] = fmaxf(m, 1e-20f) * (1.0f/16129.0f);
    }}}}}}}}
  }
  GSYNC();

  // ---- P1: int8 pack (uidx layout matching scan) + ES scan on WG0 ----
  for(int i = bid*512 + tid; i < 262144; i += 131072){
    int l = i >> 16;
    int uidx = i & 65535;
    int dw = uidx & 3;
    int kg = (uidx >> 2) & 127;
    int q  = (uidx >> 9) & 3;
    int rr = (uidx >> 11) & 7;
    int js = uidx >> 14;
    int row = rr*128 + kg;
    int k0  = js*64 + q*16 + dw*4;
    const float* W = (l==0)?A.hh0:(l==1)?A.hh1:(l==2)?A.hh2:A.hh3;
    float inv = 1.0f / (A.zsc[l*1024 + row] * 127.0f);
    u32 outv = 0;
    #pragma unroll
    for(int b=0;b<4;b++){
      float v = W[(size_t)row*256 + k0 + b];
      int q8 = max(-127, min(127, __float2int_rn(v * inv)));
      outv |= ((u32)(q8 & 0xff)) << (8*b);
    }
    A.W8[i] = outv;
  }
  if(bid == 0){
    float* xs = (float*)smem;                  // [300][128] = 150 KB
    for(int i=tid; i<38400; i+=512) xs[i] = A.xT[i];
    __syncthreads();
    if(tid < 128){
      int b = tid;
      float av = sigf(A.alpha[b]);
      float gv = sigf(A.gamma[b]);
      float S0[7];
      #pragma unroll
      for(int i=0;i<7;i++){ S0[i] = __expf(A.iseas[b*7+i]); A.ST[i*128+b] = S0[i]; }
      A.ST[7*128+b] = S0[0];
      float q0=S0[1],q1=S0[2],q2=S0[3],q3=S0[4],q4=S0[5],q5=S0[6],q6=S0[0];
      float lvl = xs[b]/S0[0];
      A.lvlT[b] = lvl;
      for(int t=1;t<300;t++){
        float xt = xs[t*128+b];
        float s  = q0;
        lvl = av*(xt/s) + (1.0f-av)*lvl;
        float sn = gv*(xt/lvl) + (1.0f-gv)*s;
        q0=q1;q1=q2;q2=q3;q3=q4;q4=q5;q5=q6;q6=sn;
        A.lvlT[t*128+b]   = lvl;
        A.ST[(t+7)*128+b] = sn;
      }
    }
  }
  GSYNC();

  // ---- 4 layers: gemm phase + scan phase ----
  gemm_body<true >(A, smem, nullptr, A.wT0, A.bs0, A.xz);  GSYNC();
  scan_body(A, smem, 0, 10, 1, A.xz, A.yA, nullptr);       GSYNC();
  gemm_body<false>(A, smem, A.yA, A.wT1, A.bs1, A.xz);     GSYNC();
  scan_body(A, smem, 1, 20, 2, A.xz, A.yB, nullptr);       GSYNC();
  gemm_body<false>(A, smem, A.yB, A.wT2, A.bs2, A.xz);     GSYNC();
  scan_body(A, smem, 2, 20, 2, A.xz, A.yA, nullptr);       GSYNC();
  gemm_body<false>(A, smem, A.yA, A.wT3, A.bs3, A.xz);     GSYNC();
  scan_body(A, smem, 3, 60, 6, A.xz, A.yA, A.yB);          GSYNC();

  // ---- P10a: head GEMM (virtual blocks 0..341) ----
  {
    float* v  = (float*)smem;                  // [8][256]
    float* h2 = v + 2048;                      // [8][256]
    for(int vb = bid; vb < 342; vb += 256){
      const int m0 = vb*8;
      for(int idx=tid; idx<2048; idx+=512){
        int p = idx >> 8, c = idx & 255;
        int m = m0 + p;
        v[p*256+c] = (m < NM) ? A.yA[(size_t)m*256+c] : 0.f;
      }
      __syncthreads();
      if(tid < 256){
        float acc[8];
        float bz = A.linb[tid];
        #pragma unroll
        for(int p=0;p<8;p++) acc[p] = bz;
        #pragma unroll 4
        for(int f=0; f<256; f++){
          float w = A.linWT[f*256+tid];
          #pragma unroll
          for(int p=0;p<8;p++) acc[p] += w * v[p*256+f];
        }
        #pragma unroll
        for(int p=0;p<8;p++) h2[p*256+tid] = tanh_(acc[p]);
      }
      __syncthreads();
      if(tid < 224){
        int o = tid % 28, p = tid / 28;
        int m = m0 + p;
        if(m < NM){
          float a = A.scb[o];
          for(int f=0; f<256; f++) a += A.scT[f*28+o] * h2[p*256+f];
          int t = m / 10, j = m - t*10;
          float* o0 = A.out;                 // prediction_values (245,128,28)
          float* o3 = A.out + 1759744;       // rnn_out (273,128,28)
          for(int b=j; b<128; b+=10){
            size_t idx = (size_t)t*3584 + b*28 + o;
            o3[idx] = a;
            if(t < 245) o0[idx] = a;
          }
          if(t == 272){
            int col = (o < 21) ? (286+o) : (279+o);
            float* o2 = A.out + 1756160;     // holdout_prediction (128,28)
            for(int b=j; b<128; b+=10){
              float hv = a * A.ST[col*128 + b] * A.lvlT[299*128 + b];
              o2[b*28 + o] = (hv > 0.0f) ? hv : 0.0f;
            }
          }
        }
      }
      __syncthreads();
    }
  }
  // ---- P10b: actual_values + hav (flat grid-stride) ----
  for(int i0 = bid*512 + tid; i0 < N_O0 + 3584; i0 += 131072){
    int i = i0;
    if(i < N_O0){
      int o = i % 28;
      int b = (i/28) % 128;
      int t = i/(28*128);
      int c = 28 + t + o;
      A.out[878080 + i] = A.xT[c*128+b] / A.ST[c*128+b] / A.lvlT[(27+t)*128+b];
    } else {
      i -= N_O0;
      int b = i/28, o = i%28;
      int col = (o < 21) ? (286+o) : (279+o);
      float Sm = A.ST[col*128 + b];
      float lv = A.lvlT[299*128 + b];
      A.out[2738176 + i] = A.val[i];
      A.out[2741760 + i] = A.val[i] / Sm / lv;
    }
  }
  #undef GSYNC
}

extern "C" void kernel_launch(void* const* d_in, const int* in_sizes, int n_in,
                              void* d_out, int out_size, void* d_ws, size_t ws_size,
                              hipStream_t stream){
  (void)in_sizes; (void)n_in; (void)out_size; (void)ws_size;
  MegaArgs A;
  A.x     = (const float*)d_in[0];
  A.val   = (const float*)d_in[1];
  A.alpha = (const float*)d_in[2];
  A.gamma = (const float*)d_in[3];
  A.iseas = (const float*)d_in[4];
  A.cats  = (const float*)d_in[5];
  A.mp    = (const float*)d_in[6];
  A.wi0 = (const float*)d_in[7];  A.hh0 = (const float*)d_in[8];  A.bs0 = (const float*)d_in[9];
  A.wi1 = (const float*)d_in[10]; A.hh1 = (const float*)d_in[11]; A.bs1 = (const float*)d_in[12];
  A.wi2 = (const float*)d_in[13]; A.hh2 = (const float*)d_in[14]; A.bs2 = (const float*)d_in[15];
  A.wi3 = (const float*)d_in[16]; A.hh3 = (const float*)d_in[17]; A.bs3 = (const float*)d_in[18];
  A.linW = (const float*)d_in[19];
  A.linb = (const float*)d_in[20];
  A.scW  = (const float*)d_in[21];
  A.scb  = (const float*)d_in[22];
  A.out  = (float*)d_out;

  float* Fw = (float*)d_ws;
  A.ST    = Fw;                  // 39296
  A.lvlT  = A.ST   + 39296;      // 38400
  A.xT    = A.lvlT + 38400;      // 38400
  A.xz    = A.xT   + 38400;      // 2795520
  A.yA    = A.xz   + 2795520;    // 698880
  A.yB    = A.yA   + 698880;     // 698880
  A.wT0   = A.yB   + 698880;     // 50176
  A.wT1   = A.wT0  + 50176;      // 262144
  A.wT2   = A.wT1  + 262144;     // 262144
  A.wT3   = A.wT2  + 262144;     // 262144
  A.linWT = A.wT3  + 262144;     // 65536
  A.scT   = A.linWT+ 65536;      // 7168
  A.zsc   = A.scT  + 7168;       // 4096
  A.W8    = (u32*)(A.zsc + 4096);// 262144 u32

  void* kargs[] = { (void*)&A };
  hipLaunchCooperativeKernel((const void*)k_mega, dim3(256), dim3(512),
                             kargs, 0, stream);
}

// Round 9
// 958.612 us; speedup vs baseline: 2.9929x; 2.9929x over previous
//
#include <hip/hip_runtime.h>

typedef unsigned int u32;

static __device__ __forceinline__ float sigf (float x){ return 1.0f/(1.0f+__expf(-x)); }
static __device__ __forceinline__ float tanh_(float x){ return 2.0f/(1.0f+__expf(-2.0f*x)) - 1.0f; }

#define NM 2730            // 273*10 distinct (t, j=b%10) rows
#define N_O0 878080        // 245*128*28

static __device__ __forceinline__ int dot4(u32 a, u32 b, int acc){
#if __has_builtin(__builtin_amdgcn_sdot4)
  return __builtin_amdgcn_sdot4((int)a, (int)b, acc, false);
#else
  int s = acc;
  #pragma unroll
  for(int i=0;i<4;i++){
    int av = (int)((signed char)((a >> (8*i)) & 0xffu));
    int bv = (int)((signed char)((b >> (8*i)) & 0xffu));
    s += av*bv;
  }
  return s;
#endif
}

// ---- fused prep: xT + 6 transposes + Whh row scales (unchanged R1) ----
__global__ __launch_bounds__(256) void k_prep(
    const float* __restrict__ x,     float* __restrict__ xT,
    const float* __restrict__ wi0,   float* __restrict__ wT0,
    const float* __restrict__ wi1,   float* __restrict__ wT1,
    const float* __restrict__ wi2,   float* __restrict__ wT2,
    const float* __restrict__ wi3,   float* __restrict__ wT3,
    const float* __restrict__ lw,    float* __restrict__ lwT,
    const float* __restrict__ sw,    float* __restrict__ swT,
    const float* __restrict__ h0, const float* __restrict__ h1,
    const float* __restrict__ h2, const float* __restrict__ h3,
    float* __restrict__ zsc){
  int i = blockIdx.x*256 + threadIdx.x;
  if(i < 38400){                    // xT
    int t = i >> 7, b = i & 127;
    xT[i] = x[b*300 + t];
    return;
  }
  i -= 38400;
  if(i < 50176){ int c=i/1024, r=i-c*1024; wT0[i] = wi0[r*49 + c];  return; }
  i -= 50176;
  if(i < 262144){ int c=i>>10, r=i&1023; wT1[i] = wi1[r*256 + c];   return; }
  i -= 262144;
  if(i < 262144){ int c=i>>10, r=i&1023; wT2[i] = wi2[r*256 + c];   return; }
  i -= 262144;
  if(i < 262144){ int c=i>>10, r=i&1023; wT3[i] = wi3[r*256 + c];   return; }
  i -= 262144;
  if(i < 65536){ int c=i>>8, r=i&255; lwT[i] = lw[r*256 + c];       return; }
  i -= 65536;
  if(i < 7168){ int c=i/28, r=i-c*28; swT[i] = sw[r*256 + c];       return; }
  i -= 7168;
  if(i < 4096){                     // per-row absmax scale (int8)
    int l = i >> 10, r = i & 1023;
    const float* W = (l==0)?h0:(l==1)?h1:(l==2)?h2:h3;
    const float4* p = (const float4*)(W + (size_t)r*256);
    float m = 0.f;
    #pragma unroll 8
    for(int q=0;q<64;q++){
      float4 v = p[q];
      m = fmaxf(m, fmaxf(fmaxf(fabsf(v.x),fabsf(v.y)), fmaxf(fabsf(v.z),fabsf(v.w))));
    }
    zsc[i] = fmaxf(m, 1e-20f) * (1.0f/16129.0f);   // rowmax/(127*127)
  }
}

// ---- fused int8 pack (v9 uidx layout) + LDS-staged ES scan ----
// pack (blocks 0..1023): per-layer u32 idx uidx: dw=uidx&3, kg=(uidx>>2)&127,
// q=(uidx>>9)&3, rr=(uidx>>11)&7, js=uidx>>14 ; row=rr*128+kg ;
// k0=js*64+q*16+dw*4  (matches k_scan8's Wb/hq indexing).
// block 1024: ES scan with x staged in LDS (kills the 300-step
// global-latency chain; ~35us -> ~8us).
__global__ __launch_bounds__(256) void k_packes(
    const float* __restrict__ h0, const float* __restrict__ h1,
    const float* __restrict__ h2, const float* __restrict__ h3,
    const float* __restrict__ zsc, u32* __restrict__ W8,
    const float* __restrict__ xT, const float* __restrict__ alpha,
    const float* __restrict__ gamma, const float* __restrict__ iseas,
    float* __restrict__ ST, float* __restrict__ lvlT){
  __shared__ float xs[128*301];              // 154 KB (pad 301: bank-spread)
  if(blockIdx.x < 1024){
    int i = blockIdx.x*256 + threadIdx.x;      // 0..262143
    int l = i >> 16;
    int uidx = i & 65535;
    int dw = uidx & 3;
    int kg = (uidx >> 2) & 127;
    int q  = (uidx >> 9) & 3;
    int rr = (uidx >> 11) & 7;
    int js = uidx >> 14;
    int row = rr*128 + kg;
    int k0  = js*64 + q*16 + dw*4;
    const float* W = (l==0)?h0:(l==1)?h1:(l==2)?h2:h3;
    float inv = 1.0f / (zsc[l*1024 + row] * 127.0f);
    u32 out = 0;
    #pragma unroll
    for(int b=0;b<4;b++){
      float v = W[(size_t)row*256 + k0 + b];
      int q8 = max(-127, min(127, __float2int_rn(v * inv)));
      out |= ((u32)(q8 & 0xff)) << (8*b);
    }
    W8[i] = out;
    return;
  }
  // ES scan block: stage xT -> LDS (coalesced), then 128-thread scan
  for(int i=threadIdx.x; i<38400; i+=256){
    int t = i >> 7, b = i & 127;
    xs[b*301 + t] = xT[i];
  }
  __syncthreads();
  int b = threadIdx.x;
  if(b >= 128) return;
  float a = sigf(alpha[b]);
  float g = sigf(gamma[b]);
  float S0[7];
  #pragma unroll
  for(int i=0;i<7;i++){ S0[i] = __expf(iseas[b*7+i]); ST[i*128+b] = S0[i]; }
  ST[7*128+b] = S0[0];
  float q0=S0[1],q1=S0[2],q2=S0[3],q3=S0[4],q4=S0[5],q5=S0[6],q6=S0[0];
  float lvl = xs[b*301]/S0[0];
  lvlT[b] = lvl;
  for(int t=1;t<300;t++){
    float xt = xs[b*301 + t];
    float s  = q0;
    lvl = a*(xt/s) + (1.0f-a)*lvl;
    float sn = g*(xt/lvl) + (1.0f-g)*s;
    q0=q1;q1=q2;q2=q3;q3=q4;q4=q5;q5=q6;q6=sn;
    lvlT[t*128+b]   = lvl;
    ST[(t+7)*128+b] = sn;
  }
}

// ---- gemm for layer 1: window_input built on the fly (unchanged R1) ----
__global__ __launch_bounds__(256) void k_gemm1(
    const float* __restrict__ xT, const float* __restrict__ ST,
    const float* __restrict__ lvlT, const float* __restrict__ cats,
    const float* __restrict__ mp,
    const float* __restrict__ WT,   // [49][1024] f32
    const float* __restrict__ bias, // [1024] f32
    float* __restrict__ Z){
  __shared__ float Xs[8][52];
  const int tid = threadIdx.x;
  const int m0 = blockIdx.x*8;
  for(int idx=tid; idx<8*49; idx+=256){
    int p = idx/49, f = idx - p*49;
    int m = m0+p;
    float v = 0.f;
    if(m < NM){
      int tt = m/10, jj = m - (m/10)*10;
      if(f < 28){
        int c = tt + f;
        v = xT[c*128 + jj] / ST[c*128 + jj] / lvlT[(tt+27)*128 + jj];
      } else if(f < 48){
        v = cats[jj*20 + (f-28)];
      } else {
        v = mp[0];
      }
    }
    Xs[p][f] = v;
  }
  __syncthreads();
  float acc0[8], acc1[8], acc2[8], acc3[8];
  {
    float b0 = bias[tid];
    float b1 = bias[tid+256];
    float b2 = bias[tid+512];
    float b3 = bias[tid+768];
    #pragma unroll
    for(int p=0;p<8;p++){ acc0[p]=b0; acc1[p]=b1; acc2[p]=b2; acc3[p]=b3; }
  }
  #pragma unroll 7
  for(int f=0; f<49; f++){
    float w0 = WT[f*1024 + tid      ];
    float w1 = WT[f*1024 + tid+256  ];
    float w2 = WT[f*1024 + tid+512  ];
    float w3 = WT[f*1024 + tid+768  ];
    #pragma unroll
    for(int p=0;p<8;p++){
      float xv = Xs[p][f];
      acc0[p] += w0*xv; acc1[p] += w1*xv; acc2[p] += w2*xv; acc3[p] += w3*xv;
    }
  }
  for(int p=0;p<8;p++){
    int m = m0+p;
    if(m < NM){
      float* zb = Z + m*1024 + tid;
      zb[0]=acc0[p]; zb[256]=acc1[p]; zb[512]=acc2[p]; zb[768]=acc3[p];
    }
  }
}

// ---- batched xz = X @ WihT + b (unchanged R1) ----
__global__ __launch_bounds__(256) void k_gemm(const float* __restrict__ X,
                                              const float* __restrict__ WT,   // [256][1024] f32
                                              const float* __restrict__ bias, // [1024] f32
                                              float* __restrict__ Z){
  __shared__ float Xs[8][256];
  const int tid = threadIdx.x;
  const int m0 = blockIdx.x*8;
  for(int p=0;p<8;p++){
    int m = m0+p;
    Xs[p][tid] = (m < NM) ? X[m*256+tid] : 0.0f;
  }
  __syncthreads();
  float acc0[8], acc1[8], acc2[8], acc3[8];
  {
    float b0 = bias[tid];
    float b1 = bias[tid+256];
    float b2 = bias[tid+512];
    float b3 = bias[tid+768];
    #pragma unroll
    for(int p=0;p<8;p++){ acc0[p]=b0; acc1[p]=b1; acc2[p]=b2; acc3[p]=b3; }
  }
  #pragma unroll 4
  for(int f=0; f<256; f++){
    float w0 = WT[f*1024 + tid      ];
    float w1 = WT[f*1024 + tid+256  ];
    float w2 = WT[f*1024 + tid+512  ];
    float w3 = WT[f*1024 + tid+768  ];
    #pragma unroll
    for(int p=0;p<8;p++){
      float xv = Xs[p][f];
      acc0[p] += w0*xv; acc1[p] += w1*xv; acc2[p] += w2*xv; acc3[p] += w3*xv;
    }
  }
  for(int p=0;p<8;p++){
    int m = m0+p;
    if(m < NM){
      float* zb = Z + m*1024 + tid;
      zb[0]=acc0[p]; zb[256]=acc1[p]; zb[512]=acc2[p]; zb[768]=acc3[p];
    }
  }
}

// ---- LSTM scan: CHAMPION v9 structure, explicit in-loop L2 weight
// stream (the codegen R1 actually ran at 267.7us/0.98us-per-step —
// established per-CU floor across 7 structural variants). ----
__global__ __launch_bounds__(512) void k_scan8(
    const float* __restrict__ Z,
    const u32* __restrict__ W8,    // packed int8 weights (256 KB)
    const float* __restrict__ zsc, // [1024] per-row z scales
    float* __restrict__ Y,
    const float* __restrict__ RES,
    int d){
  __shared__ __align__(16) u32 h8[64];   // 256 int8 h
  __shared__ int   zp[4][1024];          // 16 KB partials
  __shared__ float sc[1024];             // 4 KB row scales
  const int tid = threadIdx.x;
  const int chain = blockIdx.x;
  const int j = chain % 10;
  const int r = chain / 10;
  const int ns = (273 - r + d - 1)/d;
  const int kg = tid & 127;
  const int js = tid >> 7;
  const uint4* Wb = (const uint4*)W8 + (size_t)js*4096 + kg;
  const uint4* hq = (const uint4*)h8 + js*4;

  for(int i=tid;i<1024;i+=512) sc[i] = zsc[i];
  if(tid < 64) h8[tid] = 0u;
  float cst = 0.0f;
  __syncthreads();

  int t = r;
  for(int s=0; s<ns; s++, t+=d){
    const size_t row = (size_t)(t*10 + j);
    float zv0=0.f, zv1=0.f, zv2=0.f, zv3=0.f, rv=0.f;
    if(tid < 256){                       // prefetch (consumed after barrier)
      const float* zb = Z + row*1024;
      zv0 = zb[tid]; zv1 = zb[tid+256]; zv2 = zb[tid+512]; zv3 = zb[tid+768];
      if(RES) rv = RES[row*256 + tid];
    }
    int a0=0,a1=0,a2=0,a3=0,a4=0,a5=0,a6=0,a7=0;
    #pragma unroll
    for(int q=0;q<4;q++){
      uint4 h4 = hq[q];                  // broadcast: 16 h int8
      #pragma unroll
      for(int rr=0;rr<8;rr++){
        uint4 w = Wb[rr*512 + q*128];    // L2 stream (the floor)
        int* ap = (rr==0)?&a0:(rr==1)?&a1:(rr==2)?&a2:(rr==3)?&a3:
                  (rr==4)?&a4:(rr==5)?&a5:(rr==6)?&a6:&a7;
        int acc = *ap;
        acc = dot4(w.x, h4.x, acc);
        acc = dot4(w.y, h4.y, acc);
        acc = dot4(w.z, h4.z, acc);
        acc = dot4(w.w, h4.w, acc);
        *ap = acc;
      }
    }
    zp[js][       kg] = a0;
    zp[js][128  + kg] = a1;
    zp[js][256  + kg] = a2;
    zp[js][384  + kg] = a3;
    zp[js][512  + kg] = a4;
    zp[js][640  + kg] = a5;
    zp[js][768  + kg] = a6;
    zp[js][896  + kg] = a7;
    __syncthreads();
    if(tid < 256){
      const int u = tid;
      int si = zp[0][u]     + zp[1][u]     + zp[2][u]     + zp[3][u];
      int sf = zp[0][u+256] + zp[1][u+256] + zp[2][u+256] + zp[3][u+256];
      int sg = zp[0][u+512] + zp[1][u+512] + zp[2][u+512] + zp[3][u+512];
      int so = zp[0][u+768] + zp[1][u+768] + zp[2][u+768] + zp[3][u+768];
      float zi = zv0 + sc[u]     * (float)si;
      float zf = zv1 + sc[u+256] * (float)sf;
      float zg = zv2 + sc[u+512] * (float)sg;
      float zo = zv3 + sc[u+768] * (float)so;
      float c  = sigf(zf)*cst + sigf(zi)*tanh_(zg);
      float h  = sigf(zo)*tanh_(c);
      cst = c;
      int hqi = __float2int_rn(h * 127.0f);
      hqi = max(-127, min(127, hqi));
      ((signed char*)h8)[u] = (signed char)hqi;
      Y[row*256 + u] = h + rv;
    }
    // LDS-only fence: wait DS ops, barrier, but do NOT drain vmcnt —
    // the Y store drains under the next step's compute.
    asm volatile("s_waitcnt lgkmcnt(0)\n\ts_barrier" ::: "memory");
  }
}

// ---- head: h=tanh(Y4@linW.T+lb); rnn=h@scW.T+sb -> COMPACT rnn_small.
// No broadcast scatter here (that was ~1.86M scalar stride-280 stores). ----
__global__ __launch_bounds__(256) void k_head(const float* __restrict__ Y4,
    const float* __restrict__ LWT,  // [256][256] f32 (linWT [f][u])
    const float* __restrict__ lb,
    const float* __restrict__ SWT,  // [256][28] f32  (scoreT [f][o])
    const float* __restrict__ sb,
    float* __restrict__ rnnS){      // [2730][28]
  __shared__ float v [8][256];
  __shared__ float h2[8][256];
  const int tid = threadIdx.x;
  const int m0 = blockIdx.x*8;
  for(int p=0;p<8;p++){
    int m = m0+p;
    v[p][tid] = (m<NM) ? Y4[m*256+tid] : 0.0f;
  }
  __syncthreads();
  float acc[8];
  float bz = lb[tid];
  #pragma unroll
  for(int p=0;p<8;p++) acc[p]=bz;
  #pragma unroll 4
  for(int f=0; f<256; f++){
    float w = LWT[f*256+tid];
    #pragma unroll
    for(int p=0;p<8;p++) acc[p] += w * v[p][f];
  }
  #pragma unroll
  for(int p=0;p<8;p++) h2[p][tid] = tanh_(acc[p]);
  __syncthreads();
  if(tid < 224){
    int o = tid % 28, p = tid / 28;
    int m = m0 + p;
    if(m < NM){
      float a = sb[o];
      for(int f=0; f<256; f++) a += SWT[f*28+o] * h2[p][f];
      rnnS[m*28 + o] = a;          // coalesced compact store
    }
  }
}

// ---- outputs: everything coalesced.
// blocks 0..244: actual_values tile per t (LDS-transposed: coalesced
// b-fastest reads -> padded [28][132] tile -> coalesced 3584-contig writes).
// blocks 245..: grid-stride over {o3+o0 broadcast, holdout, hav} with
// output-linear indexing (coalesced stores; reads are 280 L2-hot floats/t).
__global__ __launch_bounds__(256) void k_outs(
    const float* __restrict__ rnnS, const float* __restrict__ ST,
    const float* __restrict__ lvlT, const float* __restrict__ xT,
    const float* __restrict__ val,  float* __restrict__ out,
    int nblk){
  const int tid = threadIdx.x;
  const int bid = blockIdx.x;
  if(bid < 245){                       // actual_values, t = bid
    __shared__ float av[28*132];
    const int t = bid;
    for(int i=tid; i<28*128; i+=256){
      int o = i >> 7, b = i & 127;
      int c = 28 + t + o;
      av[o*132 + b] = xT[c*128+b] / ST[c*128+b] / lvlT[(27+t)*128+b];
    }
    __syncthreads();
    for(int i=tid; i<3584; i+=256){
      int b = i/28, o = i - b*28;
      out[878080 + t*3584 + i] = av[o*132 + b];
    }
    return;
  }
  const int stride = (nblk - 245)*256;
  for(int i0 = (bid-245)*256 + tid; i0 < 978432 + 3584 + 3584; i0 += stride){
    int i = i0;
    if(i < 978432){                    // rnn_out (+ prediction_values)
      int t = i/3584; int rr = i - t*3584;
      int b = rr/28;  int o = rr - b*28;
      int j = b % 10;
      float a = rnnS[(t*10 + j)*28 + o];
      out[1759744 + i] = a;
      if(t < 245) out[i] = a;
    } else { i -= 978432;
      if(i < 3584){                    // holdout_prediction
        int b = i/28, o = i - (i/28)*28;
        int j = b % 10;
        float a = rnnS[(2720 + j)*28 + o];
        int col = (o < 21) ? (286+o) : (279+o);
        float hv = a * ST[col*128 + b] * lvlT[299*128 + b];
        out[1756160 + i] = (hv > 0.0f) ? hv : 0.0f;
      } else { i -= 3584;              // hav + hav_norm
        int b = i/28, o = i - (i/28)*28;
        int col = (o < 21) ? (286+o) : (279+o);
        float Sm = ST[col*128 + b];
        float lv = lvlT[299*128 + b];
        out[2738176 + i] = val[i];
        out[2741760 + i] = val[i] / Sm / lv;
      }
    }
  }
}

extern "C" void kernel_launch(void* const* d_in, const int* in_sizes, int n_in,
                              void* d_out, int out_size, void* d_ws, size_t ws_size,
                              hipStream_t stream){
  (void)in_sizes; (void)n_in; (void)out_size; (void)ws_size;
  const float* x     = (const float*)d_in[0];
  const float* val   = (const float*)d_in[1];
  const float* alpha = (const float*)d_in[2];
  const float* gamma = (const float*)d_in[3];
  const float* iseas = (const float*)d_in[4];
  const float* cats  = (const float*)d_in[5];
  const float* mp    = (const float*)d_in[6];
  const float* Wih[4]  = {(const float*)d_in[7],  (const float*)d_in[10], (const float*)d_in[13], (const float*)d_in[16]};
  const float* Whh[4]  = {(const float*)d_in[8],  (const float*)d_in[11], (const float*)d_in[14], (const float*)d_in[17]};
  const float* bias[4] = {(const float*)d_in[9],  (const float*)d_in[12], (const float*)d_in[15], (const float*)d_in[18]};
  const float* linW  = (const float*)d_in[19];
  const float* linb  = (const float*)d_in[20];
  const float* scW   = (const float*)d_in[21];
  const float* scb   = (const float*)d_in[22];

  // ---- workspace layout: f32 region, u32 packed-int8 region, rnn_small ----
  float* Fw   = (float*)d_ws;
  float* ST   = Fw;                 // 39296
  float* lvlT = ST   + 39296;       // 38400
  float* xT   = lvlT + 38400;       // 38400
  float* xz   = xT   + 38400;       // 2795520
  float* yA   = xz   + 2795520;     // 698880  (L1 out / L3 out / L4 out)
  float* yB   = yA   + 698880;      // 698880  (L2 out, residual)
  float* wihT[4];
  wihT[0] = yB + 698880;            // 50176
  wihT[1] = wihT[0] + 50176;        // 262144
  wihT[2] = wihT[1] + 262144;
  wihT[3] = wihT[2] + 262144;
  float* linWT = wihT[3] + 262144;  // 65536
  float* scT   = linWT + 65536;     // 7168
  float* zsc   = scT   + 7168;      // 4096 (4 layers x 1024)
  u32*   W8all = (u32*)(zsc + 4096);// 4 x 65536 u32 = 1 MB
  float* rnnS  = (float*)(W8all + 262144); // 2730*28 = 76440

  // ---- prep: xT + transposes + row scales (1 launch) ----
  k_prep<<<3718, 256, 0, stream>>>(x, xT,
      Wih[0], wihT[0], Wih[1], wihT[1], Wih[2], wihT[2], Wih[3], wihT[3],
      linW, linWT, scW, scT,
      Whh[0], Whh[1], Whh[2], Whh[3], zsc);

  // ---- int8 pack (blocks 0..1023) + LDS-staged ES scan (block 1024) ----
  k_packes<<<1025, 256, 0, stream>>>(Whh[0], Whh[1], Whh[2], Whh[3], zsc, W8all,
                                     xT, alpha, gamma, iseas, ST, lvlT);

  // ---- 4 LSTM layers: Wih GEMM (win folded into L1) + int8 scan ----
  const int    dlt[4]    = {1, 2, 2, 6};
  const int    chains[4] = {10, 20, 20, 60};
  const float* Xin[4]    = {nullptr, yA, yB, yA};
  float*       Yout[4]   = {yA, yB, yA, yA};
  for(int l=0;l<4;l++){
    if(l == 0)
      k_gemm1<<<(NM+7)/8, 256, 0, stream>>>(xT, ST, lvlT, cats, mp,
                                            wihT[0], bias[0], xz);
    else
      k_gemm<<<(NM+7)/8, 256, 0, stream>>>(Xin[l], wihT[l], bias[l], xz);
    k_scan8<<<chains[l], 512, 0, stream>>>(xz, W8all + l*65536, zsc + l*1024,
                                           Yout[l],
                                           (l==3) ? yB : (const float*)nullptr, dlt[l]);
  }

  // ---- head (compact rnn) + coalesced output materialization ----
  k_head<<<(NM+7)/8, 256, 0, stream>>>(yA, linWT, linb, scT, scb, rnnS);
  const int nblk = 245 + 1024;
  k_outs<<<nblk, 256, 0, stream>>>(rnnS, ST, lvlT, xT, val, (float*)d_out, nblk);
}